// Round 2
// baseline (575.264 us; speedup 1.0000x reference)
//
#include <hip/hip_runtime.h>
#include <stdint.h>

// Problem: B=16 H=8 L=512 D=64; out = (output[BH,L,D], attn[BH,L,L]) concat.
#define Bn 16
#define Hn 8
#define Ln 512
#define Dn 64
#define BHn (Bn*Hn)
#define ROWS 16            // query rows per block
#define THREADS 256
#define PSTR 520           // Ps row stride in floats (520%32==8 -> conflict-free PV reads)
#define VT 64              // V tile rows staged in LDS
#define AOFF ((size_t)BHn*Ln*Dn)   // element offset of attn within d_out

__device__ __forceinline__ float bf2f(uint16_t u){ return __uint_as_float(((uint32_t)u)<<16); }
__device__ __forceinline__ uint16_t f2bf(float f){
  uint32_t x = __float_as_uint(f);
  return (uint16_t)((x + 0x7FFFu + ((x>>16)&1u)) >> 16);   // RNE
}
__device__ __forceinline__ uint32_t pack2(float a, float b){
  return (uint32_t)f2bf(a) | ((uint32_t)f2bf(b)<<16);
}
__device__ __forceinline__ void unpack8(uint4 w, float* f){
  f[0]=__uint_as_float(w.x<<16); f[1]=__uint_as_float(w.x&0xFFFF0000u);
  f[2]=__uint_as_float(w.y<<16); f[3]=__uint_as_float(w.y&0xFFFF0000u);
  f[4]=__uint_as_float(w.z<<16); f[5]=__uint_as_float(w.z&0xFFFF0000u);
  f[6]=__uint_as_float(w.w<<16); f[7]=__uint_as_float(w.w&0xFFFF0000u);
}
// sentinel: fp32 -10000.0 or bf16 -9984.0 -> 1e9; "other values subtracted as-is" (they are 0.0)
__device__ __forceinline__ float maskterm(float mv){ return (mv < -9000.f) ? 1e9f : mv; }

// BF=true: inputs/outputs are bf16 storage; BF=false: fp32 storage.
template<bool BF>
__device__ __forceinline__ void attn_body(const void* __restrict__ qp, const void* __restrict__ kp,
                                          const void* __restrict__ vp, const void* __restrict__ mp,
                                          void* __restrict__ outp, float* Ps, float* Vs)
{
  const int t  = threadIdx.x;
  const int bh = blockIdx.y;
  const int i0 = blockIdx.x * ROWS;
  const int b  = bh >> 3;               // bh / H
  const size_t base = (size_t)bh * Ln * Dn;

  // ---------------- Phase 1: S = Q K^T / 8  (lane owns cols j=t and j=t+256) ----
  float acc0[ROWS], acc1[ROWS];
  #pragma unroll
  for (int r=0;r<ROWS;++r){ acc0[r]=0.f; acc1[r]=0.f; }

  if (BF) {
    const uint16_t* q = (const uint16_t*)qp;
    const uint16_t* k = (const uint16_t*)kp;
    const uint16_t* krow0 = k + base + (size_t)t*Dn;
    const uint16_t* krow1 = krow0 + (size_t)THREADS*Dn;
    const uint16_t* qtile = q + base + (size_t)i0*Dn;
    #pragma unroll 1
    for (int c=0;c<8;++c){                       // 8 chunks of 8 bf16
      uint4 kw0 = *(const uint4*)(krow0 + c*8);
      uint4 kw1 = *(const uint4*)(krow1 + c*8);
      float k0[8], k1[8]; unpack8(kw0,k0); unpack8(kw1,k1);
      #pragma unroll
      for (int r=0;r<ROWS;++r){
        uint4 qw = *(const uint4*)(qtile + r*Dn + c*8);   // wave-uniform -> s_load
        float qf[8]; unpack8(qw,qf);
        #pragma unroll
        for (int e=0;e<8;++e){ acc0[r] += qf[e]*k0[e]; acc1[r] += qf[e]*k1[e]; }
      }
    }
  } else {
    const float* q = (const float*)qp;
    const float* k = (const float*)kp;
    const float* krow0 = k + base + (size_t)t*Dn;
    const float* krow1 = krow0 + (size_t)THREADS*Dn;
    const float* qtile = q + base + (size_t)i0*Dn;
    #pragma unroll 1
    for (int c=0;c<16;++c){                      // 16 chunks of 4 floats
      float4 k0 = *(const float4*)(krow0 + c*4);
      float4 k1 = *(const float4*)(krow1 + c*4);
      #pragma unroll
      for (int r=0;r<ROWS;++r){
        float4 qv = *(const float4*)(qtile + r*Dn + c*4); // wave-uniform -> s_load
        acc0[r] += qv.x*k0.x + qv.y*k0.y + qv.z*k0.z + qv.w*k0.w;
        acc1[r] += qv.x*k1.x + qv.y*k1.y + qv.z*k1.z + qv.w*k1.w;
      }
    }
  }

  // mask terms: sentinel -> +1e9 (subtracted). BOTH row and column terms applied
  // in fp32, exactly as the fp32 reference: (s/8 - rm) - cm. For masked rows this
  // quantizes to -1e9 exactly (ulp(1e9)=64), making the row softmax uniform over
  // unmasked columns -- reproduced here bit-faithfully by doing the same fp32 ops.
  float cm0, cm1;
  float rmv[ROWS];
  if (BF){
    const uint16_t* m=(const uint16_t*)mp;
    cm0 = maskterm(bf2f(m[b*Ln+t]));
    cm1 = maskterm(bf2f(m[b*Ln+t+THREADS]));
    #pragma unroll
    for (int r=0;r<ROWS;++r) rmv[r] = maskterm(bf2f(m[b*Ln+i0+r]));
  } else {
    const float* m=(const float*)mp;
    cm0 = maskterm(m[b*Ln+t]);
    cm1 = maskterm(m[b*Ln+t+THREADS]);
    #pragma unroll
    for (int r=0;r<ROWS;++r) rmv[r] = maskterm(m[b*Ln+i0+r]);
  }
  #pragma unroll
  for (int r=0;r<ROWS;++r){
    const float s0 = (acc0[r]*0.125f - rmv[r]);   // fp32 round here (matches ref)
    const float s1 = (acc1[r]*0.125f - rmv[r]);
    Ps[r*PSTR + t]           = s0 - cm0;          // second fp32 round (matches ref)
    Ps[r*PSTR + t + THREADS] = s1 - cm1;
  }
  __syncthreads();

  // ---------------- Phase 2: row softmax (one wave per 4 rows), write attn -----
  const int lane = t & 63;
  const int wv   = t >> 6;
  #pragma unroll
  for (int kk=0;kk<4;++kk){
    const int r = wv*4 + kk;
    float* prow = Ps + r*PSTR;
    float xs[8];
    *(float4*)&xs[0] = *(const float4*)(prow + lane*8);
    *(float4*)&xs[4] = *(const float4*)(prow + lane*8 + 4);
    float mx = xs[0];
    #pragma unroll
    for (int e=1;e<8;++e) mx = fmaxf(mx, xs[e]);
    #pragma unroll
    for (int sh=1; sh<64; sh<<=1) mx = fmaxf(mx, __shfl_xor(mx, sh));
    float es[8], sum = 0.f;
    #pragma unroll
    for (int e=0;e<8;++e){ es[e] = __expf(xs[e]-mx); sum += es[e]; }
    #pragma unroll
    for (int sh=1; sh<64; sh<<=1) sum += __shfl_xor(sum, sh);
    const float inv = 1.0f / sum;
    #pragma unroll
    for (int e=0;e<8;++e) es[e] *= inv;
    *(float4*)(prow + lane*8)     = *(float4*)&es[0];
    *(float4*)(prow + lane*8 + 4) = *(float4*)&es[4];
    const size_t aidx = (size_t)bh*Ln*Ln + (size_t)(i0+r)*Ln + lane*8;
    if (BF){
      uint4 pw; pw.x=pack2(es[0],es[1]); pw.y=pack2(es[2],es[3]);
                pw.z=pack2(es[4],es[5]); pw.w=pack2(es[6],es[7]);
      *(uint4*)((uint16_t*)outp + AOFF + aidx) = pw;
    } else {
      float* ap = (float*)outp + AOFF + aidx;
      *(float4*)ap     = *(float4*)&es[0];
      *(float4*)(ap+4) = *(float4*)&es[4];
    }
  }

  // ---------------- Phase 3: O = P V  (thread owns 1 row x 4 cols) -------------
  const int orow = t >> 4;
  const int d0   = (t & 15) * 4;
  float ox=0.f, oy=0.f, oz=0.f, ow=0.f;
  const float* prow = Ps + orow*PSTR;
  for (int jt=0; jt<Ln; jt+=VT){
    __syncthreads();
    if (BF){
      const uint16_t* vsrc = (const uint16_t*)vp + base + (size_t)jt*Dn;
      #pragma unroll
      for (int u=0;u<2;++u){
        const int f = t + u*THREADS;             // uint4 index (8 halves each)
        uint4 w = *(const uint4*)(vsrc + f*8);
        float vf[8]; unpack8(w, vf);
        float4* dst = (float4*)Vs + f*2;
        dst[0] = make_float4(vf[0],vf[1],vf[2],vf[3]);
        dst[1] = make_float4(vf[4],vf[5],vf[6],vf[7]);
      }
    } else {
      const float4* vsrc = (const float4*)((const float*)vp + base + (size_t)jt*Dn);
      float4* vdst = (float4*)Vs;
      #pragma unroll
      for (int u=0;u<4;++u){ const int f = t + u*THREADS; vdst[f] = vsrc[f]; }
    }
    __syncthreads();
    #pragma unroll
    for (int j4=0; j4<VT; j4+=4){
      float4 p = *(const float4*)(prow + jt + j4);
      const float* vr = Vs + j4*Dn + d0;
      float4 v0=*(const float4*)(vr);
      float4 v1=*(const float4*)(vr+Dn);
      float4 v2=*(const float4*)(vr+2*Dn);
      float4 v3=*(const float4*)(vr+3*Dn);
      ox += p.x*v0.x + p.y*v1.x + p.z*v2.x + p.w*v3.x;
      oy += p.x*v0.y + p.y*v1.y + p.z*v2.y + p.w*v3.y;
      oz += p.x*v0.z + p.y*v1.z + p.z*v2.z + p.w*v3.z;
      ow += p.x*v0.w + p.y*v1.w + p.z*v2.w + p.w*v3.w;
    }
  }
  const size_t oidx = base + (size_t)(i0+orow)*Dn + d0;
  if (BF){
    uint2 w2; w2.x = pack2(ox,oy); w2.y = pack2(oz,ow);
    *(uint2*)((uint16_t*)outp + oidx) = w2;
  } else {
    *(float4*)((float*)outp + oidx) = make_float4(ox,oy,oz,ow);
  }
}

extern "C" __global__ __launch_bounds__(THREADS)
void attn_kernel(const void* __restrict__ qp, const void* __restrict__ kp,
                 const void* __restrict__ vp, const void* __restrict__ mp,
                 void* __restrict__ outp)
{
  __shared__ float Ps[ROWS*PSTR];     // 33.3 KB: S tile then probs
  __shared__ float Vs[VT*Dn];         // 16 KB: V tile
  __shared__ int flags[2];

  const int t = threadIdx.x;

  // ---- storage-dtype detection from mask bit patterns (deterministic data) ----
  // fp32 mask words are only 0x00000000 / 0xC61C4000 (-10000.0f).
  // bf16 mask halfwords are only 0x0000 / 0xC61C. Patterns are mutually exclusive:
  // fp32 sets flags[0] (and possibly flags[1] via high halfword); bf16 sets only flags[1].
  if (t < 2) flags[t] = 0;
  __syncthreads();
  {
    const uint32_t* mw = (const uint32_t*)mp;
    int v32 = 0, v16 = 0;
    #pragma unroll
    for (int u=0; u<16; ++u) {
      const uint32_t w = mw[t + u*THREADS];     // first 16KB valid under both dtypes
      if (w == 0xC61C4000u) v32 = 1;
      else if ((w & 0xFFFFu) == 0xC61Cu || (w >> 16) == 0xC61Cu) v16 = 1;
    }
    if (v32) atomicOr(&flags[0], 1);
    if (v16) atomicOr(&flags[1], 1);
  }
  __syncthreads();
  const bool isBF16 = (flags[1] != 0) && (flags[0] == 0);

  if (isBF16) attn_body<true >(qp,kp,vp,mp,outp,Ps,Vs);
  else        attn_body<false>(qp,kp,vp,mp,outp,Ps,Vs);
}

extern "C" void kernel_launch(void* const* d_in, const int* in_sizes, int n_in,
                              void* d_out, int out_size, void* d_ws, size_t ws_size,
                              hipStream_t stream)
{
  (void)in_sizes; (void)n_in; (void)d_ws; (void)ws_size; (void)out_size;
  dim3 grid(Ln/ROWS, BHn);            // 32 x 128 blocks
  attn_kernel<<<grid, THREADS, 0, stream>>>(d_in[0], d_in[1], d_in[2], d_in[3], d_out);
}

// Round 3
// 258.092 us; speedup vs baseline: 2.2289x; 2.2289x over previous
//
#include <hip/hip_runtime.h>
#include <stdint.h>

// B=16 H=8 L=512 D=64; fp32 in/out (confirmed by round-2 WRITE_SIZE).
// out = concat(output[128,512,64], attn[128,512,512]) fp32.
#define Ln 512
#define Dn 64
#define BHn 128
#define AOFF ((size_t)BHn*Ln*Dn)

typedef __attribute__((ext_vector_type(8))) short short8;   // 8 bf16 (guide-verified frag type)
typedef __attribute__((ext_vector_type(4))) float f32x4;
typedef __attribute__((ext_vector_type(4))) unsigned int u32x4;
typedef __attribute__((ext_vector_type(2))) unsigned int u32x2;

#define KSTR 72     // K LDS row stride (bf16): 144B = 9*16B (odd) -> conflict-free b128 frags
#define VTSTR 136   // Vt LDS row stride (bf16): 272B = 17*16B (odd) -> conflict-free b128 frags

__device__ __forceinline__ uint16_t f2bf(float f){
  uint32_t x = __float_as_uint(f);
  return (uint16_t)((x + 0x7FFFu + ((x>>16)&1u)) >> 16);   // RNE
}
__device__ __forceinline__ float bf2f(uint16_t u){ return __uint_as_float(((uint32_t)u)<<16); }
__device__ __forceinline__ uint32_t pack2(float a, float b){
  return (uint32_t)f2bf(a) | ((uint32_t)f2bf(b)<<16);
}

extern "C" __global__ __launch_bounds__(256, 2)
void attn_mfma(const float* __restrict__ qg, const float* __restrict__ kg,
               const float* __restrict__ vg, const float* __restrict__ mg,
               float* __restrict__ outg)
{
  // LDS: QK phase: KHI[128][72] (18432B) + KLO[128][72] (18432B) = 36864B
  //      PV phase: VT[64][136] (17408B) reuses the K region
  //      CMV[512] fp32 at 36864 (persistent)
  __shared__ uint4 ldsraw[(36864 + 2048)/16];
  uint16_t* KHI = (uint16_t*)ldsraw;
  uint16_t* KLO = KHI + 128*KSTR;
  uint16_t* VT  = (uint16_t*)ldsraw;
  float*    CMV = (float*)((char*)ldsraw + 36864);

  const int t    = threadIdx.x;
  const int lane = t & 63;
  const int wv   = t >> 6;
  const int li   = lane & 15;      // MFMA n/col lane
  const int lq   = lane >> 4;      // MFMA quad
  const int bh   = blockIdx.y;
  const int b    = bh >> 3;
  const int i0   = blockIdx.x*64 + wv*16;       // wave's 16 q-rows
  const size_t base = (size_t)bh * (Ln*Dn);
  const float* mrow = mg + b*Ln;

  // ---- stage column-mask terms: sentinel(-10000) -> 1e9, else value (0) ----
  {
    float m0 = mrow[t], m1 = mrow[t+256];
    CMV[t]     = (m0 < -9000.f) ? 1e9f : m0;
    CMV[t+256] = (m1 < -9000.f) ? 1e9f : m1;
  }

  // ---- Q A-fragments (m=li, k=kt*32+lq*8+e), bf16 hi/lo split ----
  short8 qhi[2], qlo[2];
  {
    const float* qrow = qg + base + (size_t)(i0 + li)*Dn;
    #pragma unroll
    for (int kt=0; kt<2; ++kt){
      const float* p = qrow + kt*32 + lq*8;
      f32x4 x0 = *(const f32x4*)p;
      f32x4 x1 = *(const f32x4*)(p+4);
      #pragma unroll
      for (int e=0; e<8; ++e){
        float x = (e<4) ? x0[e] : x1[e-4];
        uint16_t h = f2bf(x);
        qhi[kt][e] = (short)h;
        qlo[kt][e] = (short)f2bf(x - bf2f(h));
      }
    }
  }

  // ---- S accumulators: 32 j-tiles x f32x4 (16x512 strip, C-layout) ----
  f32x4 acc[32];
  #pragma unroll
  for (int j=0; j<32; ++j) acc[j] = (f32x4)0.f;

  // ---- QK^T: 4 chunks of 128 K-rows, bf16x2 split (3 MFMAs) ----
  const int sj = t>>1, skh = t&1;   // staging: thread -> (k-row, 32-col half)
  #pragma unroll
  for (int c=0; c<4; ++c){
    __syncthreads();                 // prior chunk's frag reads done (c=0: CMV ordering)
    {
      const float* kr = kg + base + (size_t)(c*128 + sj)*Dn + skh*32;
      uint16_t* dhi = KHI + sj*KSTR + skh*32;
      uint16_t* dlo = KLO + sj*KSTR + skh*32;
      #pragma unroll
      for (int w2=0; w2<4; ++w2){
        f32x4 x0 = *(const f32x4*)(kr + w2*8);
        f32x4 x1 = *(const f32x4*)(kr + w2*8 + 4);
        uint32_t hw[4], lw[4];
        #pragma unroll
        for (int pi=0; pi<4; ++pi){
          float a0 = (pi<2) ? x0[pi*2]   : x1[(pi-2)*2];
          float a1 = (pi<2) ? x0[pi*2+1] : x1[(pi-2)*2+1];
          uint16_t h0 = f2bf(a0), h1 = f2bf(a1);
          hw[pi] = (uint32_t)h0 | ((uint32_t)h1<<16);
          lw[pi] = (uint32_t)f2bf(a0 - bf2f(h0)) | ((uint32_t)f2bf(a1 - bf2f(h1))<<16);
        }
        *(u32x4*)(dhi + w2*8) = (u32x4){hw[0],hw[1],hw[2],hw[3]};
        *(u32x4*)(dlo + w2*8) = (u32x4){lw[0],lw[1],lw[2],lw[3]};
      }
    }
    __syncthreads();
    #pragma unroll
    for (int jt=0; jt<8; ++jt){
      #pragma unroll
      for (int kt=0; kt<2; ++kt){
        const int off = (jt*16 + li)*KSTR + kt*32 + lq*8;
        short8 kh = *(const short8*)(KHI + off);
        short8 kl = *(const short8*)(KLO + off);
        f32x4 A = acc[c*8+jt];
        A = __builtin_amdgcn_mfma_f32_16x16x32_bf16(qhi[kt], kh, A, 0,0,0);
        A = __builtin_amdgcn_mfma_f32_16x16x32_bf16(qhi[kt], kl, A, 0,0,0);
        A = __builtin_amdgcn_mfma_f32_16x16x32_bf16(qlo[kt], kh, A, 0,0,0);
        acc[c*8+jt] = A;
      }
    }
  }

  // ---- mask + softmax in C-layout regs; write attn (fp32) ----
  float rml[4];
  #pragma unroll
  for (int e=0; e<4; ++e){
    float mv = mrow[i0 + lq*4 + e];
    rml[e] = (mv < -9000.f) ? 1e9f : mv;
  }
  #pragma unroll
  for (int j=0; j<32; ++j){
    float cm = CMV[j*16 + li];
    #pragma unroll
    for (int e=0; e<4; ++e){
      float s = acc[j][e]*0.125f - rml[e];   // fp32: masked rows quantize to -1e9 exactly (as ref)
      acc[j][e] = s - cm;
    }
  }
  float* attn_base = outg + AOFF + (size_t)bh*Ln*Ln;
  #pragma unroll
  for (int e=0; e<4; ++e){
    const int row = i0 + lq*4 + e;
    float mx = -3.4e38f;
    #pragma unroll
    for (int j=0; j<32; ++j) mx = fmaxf(mx, acc[j][e]);
    #pragma unroll
    for (int sh=1; sh<16; sh<<=1) mx = fmaxf(mx, __shfl_xor(mx, sh));
    float sum = 0.f;
    #pragma unroll
    for (int j=0; j<32; ++j){ float ee = __expf(acc[j][e]-mx); acc[j][e] = ee; sum += ee; }
    #pragma unroll
    for (int sh=1; sh<16; sh<<=1) sum += __shfl_xor(sum, sh);
    const float inv = 1.0f/sum;
    #pragma unroll
    for (int j=0; j<32; ++j){
      float p = acc[j][e]*inv;
      attn_base[(size_t)row*Ln + j*16 + li] = p;   // 4x64B segments per store inst
    }
  }

  // ---- PV: reload P from attn (own stores; spill-path-coherent), V^T in LDS ----
  asm volatile("s_waitcnt vmcnt(0)" ::: "memory");
  f32x4 oacc[4];
  #pragma unroll
  for (int dt=0; dt<4; ++dt) oacc[dt] = (f32x4)0.f;
  const float* arow = attn_base + (size_t)(i0 + li)*Ln;   // A-frag row m=li

  #pragma unroll
  for (int c=0; c<4; ++c){
    __syncthreads();                 // K region / previous Vt reads done
    #pragma unroll
    for (int it=0; it<2; ++it){      // stage Vt chunk: 128 j x 64 d, 4x4 reg transpose
      const int j0 = (t>>4)*4 + it*64;
      const int d0 = (t&15)*4;
      const float* vr = vg + base + (size_t)(c*128 + j0)*Dn + d0;
      f32x4 r0 = *(const f32x4*)(vr);
      f32x4 r1 = *(const f32x4*)(vr + Dn);
      f32x4 r2 = *(const f32x4*)(vr + 2*Dn);
      f32x4 r3 = *(const f32x4*)(vr + 3*Dn);
      #pragma unroll
      for (int qd=0; qd<4; ++qd){
        u32x2 w; w.x = pack2(r0[qd], r1[qd]); w.y = pack2(r2[qd], r3[qd]);
        *(u32x2*)(VT + (d0+qd)*VTSTR + j0) = w;
      }
    }
    __syncthreads();
    #pragma unroll
    for (int ktl=0; ktl<4; ++ktl){
      const float* pp = arow + c*128 + ktl*32 + lq*8;     // P A-frag from global (L2-hot)
      f32x4 p0 = *(const f32x4*)pp;
      f32x4 p1 = *(const f32x4*)(pp+4);
      short8 pfrag;
      #pragma unroll
      for (int e=0; e<8; ++e) pfrag[e] = (short)f2bf((e<4) ? p0[e] : p1[e-4]);
      #pragma unroll
      for (int dt=0; dt<4; ++dt){
        short8 vb = *(const short8*)(VT + (dt*16 + li)*VTSTR + ktl*32 + lq*8);
        oacc[dt] = __builtin_amdgcn_mfma_f32_16x16x32_bf16(pfrag, vb, oacc[dt], 0,0,0);
      }
    }
  }

  // ---- store O (16x64 per wave, C-layout) ----
  #pragma unroll
  for (int dt=0; dt<4; ++dt){
    #pragma unroll
    for (int e=0; e<4; ++e){
      outg[base + (size_t)(i0 + lq*4 + e)*Dn + dt*16 + li] = oacc[dt][e];
    }
  }
}

extern "C" void kernel_launch(void* const* d_in, const int* in_sizes, int n_in,
                              void* d_out, int out_size, void* d_ws, size_t ws_size,
                              hipStream_t stream)
{
  (void)in_sizes; (void)n_in; (void)d_ws; (void)ws_size; (void)out_size;
  dim3 grid(Ln/64, BHn);            // 8 x 128 blocks, 256 thr (4 waves x 16 rows)
  attn_mfma<<<grid, 256, 0, stream>>>((const float*)d_in[0], (const float*)d_in[1],
                                      (const float*)d_in[2], (const float*)d_in[3],
                                      (float*)d_out);
}

// Round 4
// 239.928 us; speedup vs baseline: 2.3977x; 1.0757x over previous
//
#include <hip/hip_runtime.h>
#include <stdint.h>

// B=16 H=8 L=512 D=64; fp32 in/out. out = concat(output[128,512,64], attn[128,512,512]).
// Round-4 structure: S^T via swapped MFMA operands; softmax in S^T C-layout;
// PV as O^T = V^T * P^T with P round-tripped through per-wave private LDS (bf16).
#define Ln 512
#define Dn 64
#define BHn 128
#define AOFF ((size_t)BHn*Ln*Dn)

typedef __attribute__((ext_vector_type(8))) short short8;   // 8 bf16 (4 VGPRs)
typedef __attribute__((ext_vector_type(4))) float f32x4;
typedef __attribute__((ext_vector_type(4))) unsigned int u32x4;
typedef __attribute__((ext_vector_type(2))) unsigned int u32x2;

#define KSTR  72    // K LDS row stride (halves): 144B = 9*16B odd -> conflict-free b128
#define VTSTR 136   // Vt LDS row stride (halves): 272B = 17*16B odd
#define PSTRH 136   // P chunk row stride (halves), per-wave private region

__device__ __forceinline__ uint16_t f2bf(float f){
  uint32_t x = __float_as_uint(f);
  return (uint16_t)((x + 0x7FFFu + ((x>>16)&1u)) >> 16);   // RNE
}
__device__ __forceinline__ float bf2f(uint16_t u){ return __uint_as_float(((uint32_t)u)<<16); }
__device__ __forceinline__ uint32_t pack2(float a, float b){
  return (uint32_t)f2bf(a) | ((uint32_t)f2bf(b)<<16);
}

extern "C" __global__ __launch_bounds__(256, 2)
void attn_mfma(const float* __restrict__ qg, const float* __restrict__ kg,
               const float* __restrict__ vg, const float* __restrict__ mg,
               float* __restrict__ outg)
{
  // LDS map: [0,36864): QK phase KHI[128][72]+KLO[128][72] bf16
  //                     PV phase VT[64][136] bf16 (17408B) + 4x per-wave P chunk (4352B each)
  //          [36864,38912): CMV[512] fp32 column-mask terms
  __shared__ uint4 ldsraw[(36864 + 2048)/16];
  uint16_t* KHI = (uint16_t*)ldsraw;
  uint16_t* KLO = KHI + 128*KSTR;
  uint16_t* VT  = (uint16_t*)ldsraw;
  float*    CMV = (float*)((char*)ldsraw + 36864);

  const int t    = threadIdx.x;
  const int lane = t & 63;
  const int wv   = t >> 6;
  const int li   = lane & 15;      // C-layout col; S^T col = query index i
  const int lq   = lane >> 4;      // quad
  const int bh   = blockIdx.y;
  const int b    = bh >> 3;
  const int i0   = blockIdx.x*64 + wv*16;       // wave's 16 query rows
  const size_t base = (size_t)bh*(Ln*Dn);
  const float* mrow = mg + b*Ln;

  uint16_t* PW = (uint16_t*)((char*)ldsraw + 17408 + wv*(16*PSTRH*2));  // private P chunk

  // ---- column-mask terms: sentinel -> 1e9, else value (0) ----
  {
    float m0 = mrow[t], m1 = mrow[t+256];
    CMV[t]     = (m0 < -9000.f) ? 1e9f : m0;
    CMV[t+256] = (m1 < -9000.f) ? 1e9f : m1;
  }

  // ---- Q fragments (used as B operand: lane li holds Q[i0+li][kt*32+lq*8+e]) ----
  short8 qhi[2], qlo[2];
  {
    const float* qrow = qg + base + (size_t)(i0 + li)*Dn;
    #pragma unroll
    for (int kt=0; kt<2; ++kt){
      const float* p = qrow + kt*32 + lq*8;
      f32x4 x0 = *(const f32x4*)p;
      f32x4 x1 = *(const f32x4*)(p+4);
      #pragma unroll
      for (int e=0; e<8; ++e){
        float x = (e<4) ? x0[e] : x1[e-4];
        uint16_t h = f2bf(x);
        qhi[kt][e] = (short)h;
        qlo[kt][e] = (short)f2bf(x - bf2f(h));
      }
    }
  }

  // ---- S^T accumulators: 32 j-tiles x f32x4; lane holds S^T[j=jt*16+lq*4+r][i=li] ----
  f32x4 acc[32];
  #pragma unroll
  for (int j=0; j<32; ++j) acc[j] = (f32x4)0.f;

  // ---- S^T = K Q^T: 4 chunks of 128 K-rows, bf16 hi/lo split (3 MFMAs) ----
  const int sj = t>>1, skh = t&1;
  #pragma unroll
  for (int c=0; c<4; ++c){
    __syncthreads();
    {
      const float* kr = kg + base + (size_t)(c*128 + sj)*Dn + skh*32;
      uint16_t* dhi = KHI + sj*KSTR + skh*32;
      uint16_t* dlo = KLO + sj*KSTR + skh*32;
      #pragma unroll
      for (int w2=0; w2<4; ++w2){
        f32x4 x0 = *(const f32x4*)(kr + w2*8);
        f32x4 x1 = *(const f32x4*)(kr + w2*8 + 4);
        uint32_t hw[4], lw[4];
        #pragma unroll
        for (int pi=0; pi<4; ++pi){
          float a0 = (pi<2) ? x0[pi*2]   : x1[(pi-2)*2];
          float a1 = (pi<2) ? x0[pi*2+1] : x1[(pi-2)*2+1];
          uint16_t h0 = f2bf(a0), h1 = f2bf(a1);
          hw[pi] = (uint32_t)h0 | ((uint32_t)h1<<16);
          lw[pi] = (uint32_t)f2bf(a0 - bf2f(h0)) | ((uint32_t)f2bf(a1 - bf2f(h1))<<16);
        }
        *(u32x4*)(dhi + w2*8) = (u32x4){hw[0],hw[1],hw[2],hw[3]};
        *(u32x4*)(dlo + w2*8) = (u32x4){lw[0],lw[1],lw[2],lw[3]};
      }
    }
    __syncthreads();
    #pragma unroll
    for (int jt=0; jt<8; ++jt){
      #pragma unroll
      for (int kt=0; kt<2; ++kt){
        const int off = (jt*16 + li)*KSTR + kt*32 + lq*8;   // K row = A operand (m=li)
        short8 kh = *(const short8*)(KHI + off);
        short8 kl = *(const short8*)(KLO + off);
        f32x4 A = acc[c*8+jt];
        A = __builtin_amdgcn_mfma_f32_16x16x32_bf16(kh, qhi[kt], A, 0,0,0);
        A = __builtin_amdgcn_mfma_f32_16x16x32_bf16(kl, qhi[kt], A, 0,0,0);
        A = __builtin_amdgcn_mfma_f32_16x16x32_bf16(kh, qlo[kt], A, 0,0,0);
        acc[c*8+jt] = A;
      }
    }
  }

  // ---- mask + softmax over j (per lane: own 128 j's, then quad-combine) ----
  {
    float mv = mrow[i0 + li];
    const float rmv = (mv < -9000.f) ? 1e9f : mv;
    #pragma unroll
    for (int jt=0; jt<32; ++jt){
      f32x4 cm = *(const f32x4*)(CMV + jt*16 + lq*4);
      #pragma unroll
      for (int r=0; r<4; ++r)
        acc[jt][r] = (acc[jt][r]*0.125f - rmv) - cm[r];   // fp32 rounding matches ref
    }
  }
  float mx = -3.4e38f;
  #pragma unroll
  for (int jt=0; jt<32; ++jt)
    #pragma unroll
    for (int r=0; r<4; ++r) mx = fmaxf(mx, acc[jt][r]);
  mx = fmaxf(mx, __shfl_xor(mx, 16));
  mx = fmaxf(mx, __shfl_xor(mx, 32));
  float sum = 0.f;
  #pragma unroll
  for (int jt=0; jt<32; ++jt)
    #pragma unroll
    for (int r=0; r<4; ++r){ float e = __expf(acc[jt][r]-mx); acc[jt][r] = e; sum += e; }
  sum += __shfl_xor(sum, 16);
  sum += __shfl_xor(sum, 32);
  const float inv = 1.0f/sum;

  // ---- normalize + write attn (float4 per tile: row i0+li, cols jt*16+lq*4..+3) ----
  {
    float* arow = outg + AOFF + (size_t)bh*Ln*Ln + (size_t)(i0+li)*Ln;
    #pragma unroll
    for (int jt=0; jt<32; ++jt){
      f32x4 p = acc[jt]*inv;
      acc[jt] = p;
      *(f32x4*)(arow + jt*16 + lq*4) = p;
    }
  }

  // ---- PV: O^T = V^T P^T; V^T staged in LDS, P^T chunks via private LDS ----
  f32x4 oacc[4];
  #pragma unroll
  for (int dt=0; dt<4; ++dt) oacc[dt] = (f32x4)0.f;

  #pragma unroll
  for (int c=0; c<4; ++c){
    __syncthreads();                   // prior chunk's VT reads done (c=0: K reads done)
    #pragma unroll
    for (int it=0; it<2; ++it){        // stage V^T chunk: 128 j x 64 d via 4x4 reg transpose
      const int j0 = (t>>4)*4 + it*64;
      const int d0 = (t&15)*4;
      const float* vr = vg + base + (size_t)(c*128 + j0)*Dn + d0;
      f32x4 r0 = *(const f32x4*)(vr);
      f32x4 r1 = *(const f32x4*)(vr + Dn);
      f32x4 r2 = *(const f32x4*)(vr + 2*Dn);
      f32x4 r3 = *(const f32x4*)(vr + 3*Dn);
      #pragma unroll
      for (int qd=0; qd<4; ++qd){
        u32x2 w; w.x = pack2(r0[qd], r1[qd]); w.y = pack2(r2[qd], r3[qd]);
        *(u32x2*)(VT + (d0+qd)*VTSTR + j0) = w;
      }
    }
    __syncthreads();
    // write P chunk rows (per-wave private; lane owns row li cols jtl*16+lq*4..+3)
    #pragma unroll
    for (int jtl=0; jtl<8; ++jtl){
      const f32x4 p = acc[c*8+jtl];
      u32x2 w; w.x = pack2(p[0], p[1]); w.y = pack2(p[2], p[3]);
      *(u32x2*)(PW + li*PSTRH + jtl*16 + lq*4) = w;
    }
    asm volatile("s_waitcnt lgkmcnt(0)" ::: "memory");   // P writes visible within wave
    #pragma unroll
    for (int c32=0; c32<4; ++c32){
      short8 pf = *(const short8*)(PW + li*PSTRH + c32*32 + lq*8);   // P^T B-frag
      #pragma unroll
      for (int dt=0; dt<4; ++dt){
        short8 vb = *(const short8*)(VT + (dt*16+li)*VTSTR + c32*32 + lq*8); // V^T A-frag
        oacc[dt] = __builtin_amdgcn_mfma_f32_16x16x32_bf16(vb, pf, oacc[dt], 0,0,0);
      }
    }
  }

  // ---- store O (O^T C-layout: lane holds O[i=li][d=dt*16+lq*4+r] -> float4) ----
  #pragma unroll
  for (int dt=0; dt<4; ++dt)
    *(f32x4*)(outg + base + (size_t)(i0+li)*Dn + dt*16 + lq*4) = oacc[dt];
}

extern "C" void kernel_launch(void* const* d_in, const int* in_sizes, int n_in,
                              void* d_out, int out_size, void* d_ws, size_t ws_size,
                              hipStream_t stream)
{
  (void)in_sizes; (void)n_in; (void)d_ws; (void)ws_size; (void)out_size;
  dim3 grid(Ln/64, BHn);            // 8 x 128 blocks, 256 thr (4 waves x 16 q-rows)
  attn_mfma<<<grid, 256, 0, stream>>>((const float*)d_in[0], (const float*)d_in[1],
                                      (const float*)d_in[2], (const float*)d_in[3],
                                      (float*)d_out);
}